// Round 2
// baseline (252.478 us; speedup 1.0000x reference)
//
#include <hip/hip_runtime.h>
#include <hip/hip_bf16.h>

typedef __bf16 bf16;
typedef __bf16 bf16x8 __attribute__((ext_vector_type(8)));
typedef __bf16 bf16x4 __attribute__((ext_vector_type(4)));
typedef __bf16 bf16x2 __attribute__((ext_vector_type(2)));
typedef float floatx4 __attribute__((ext_vector_type(4)));
typedef float floatx16 __attribute__((ext_vector_type(16)));
typedef int intx4 __attribute__((ext_vector_type(4)));

#define B_SZ 2
#define S_LEN 2048
#define D_DIM 1024
#define H_CNT 16
#define HD_DIM 64
#define M_ROWS 4096   // B*S
#define QSCALE 0.18033688011112042f  // 0.125 * log2(e): scores come out in base-2 domain

__device__ __forceinline__ void async_ld16(const bf16* g, bf16* s) {
    __builtin_amdgcn_global_load_lds((const __attribute__((address_space(1))) void*)g,
                                     (__attribute__((address_space(3))) void*)s, 16, 0, 0);
}

__device__ __forceinline__ floatx4 mfma16(bf16x8 a, bf16x8 b, floatx4 c) {
    return __builtin_amdgcn_mfma_f32_16x16x32_bf16(a, b, c, 0, 0, 0);
}
__device__ __forceinline__ floatx16 mfma32(bf16x8 a, bf16x8 b, floatx16 c) {
    return __builtin_amdgcn_mfma_f32_32x32x16_bf16(a, b, c, 0, 0, 0);
}

// T12 fragment assembly: one permlane32_swap fills two output words (m214v22 recipe).
__device__ __forceinline__ bf16x8 mkfrag(int a0, int a1, int b0, int b1) {
    asm("v_permlane32_swap_b32 %0, %1" : "+v"(a0), "+v"(b0));
    asm("v_permlane32_swap_b32 %0, %1" : "+v"(a1), "+v"(b1));
    intx4 q = {a0, a1, b0, b1};
    return __builtin_bit_cast(bf16x8, q);
}

// counted waitcnt that the compiler cannot reorder memory ops across
#define VMWAIT(N) asm volatile("s_waitcnt vmcnt(" #N ")" ::: "memory")

// ---------------- merged prep: input casts + all weight transposes, one launch ----------------
struct PrepArgs {
    const float* cast_src[3]; bf16* cast_dst[3];
    const float* w_src[3];    bf16* w_dst[3];
    const float* wo;          bf16* wo_t;
};
__global__ __launch_bounds__(256) void prep(PrepArgs a) {
    __shared__ bf16 tile[32][33];
    const int bx = blockIdx.x, tid = threadIdx.x;
    if (bx < 12288) {
        const int t = bx >> 12, blk = bx & 4095;
        const float* s = a.cast_src[t];
        bf16* d = a.cast_dst[t];
        size_t i = ((size_t)blk * 256 + tid) * 4;
        float4 v = *(const float4*)(s + i);
        bf16x4 o = { (bf16)v.x, (bf16)v.y, (bf16)v.z, (bf16)v.w };
        *(bf16x4*)(d + i) = o;
        return;
    }
    int tx = tid & 31, ty = tid >> 5;
    const float* src; bf16* dst; int r0, c0, C, R;
    if (bx < 15360) {
        int idx = bx - 12288;
        int z = idx >> 6, xy = idx & 63;
        int mat = z >> 4, head = z & 15;
        src = a.w_src[mat] + (size_t)head * D_DIM * HD_DIM;  // [1024][64]
        dst = a.w_dst[mat] + (size_t)head * D_DIM * HD_DIM;  // [64][1024]
        r0 = (xy & 31) * 32; c0 = (xy >> 5) * 32; C = HD_DIM; R = D_DIM;
    } else {
        int idx = bx - 15360;
        src = a.wo; dst = a.wo_t;
        r0 = (idx & 31) * 32; c0 = (idx >> 5) * 32; C = D_DIM; R = D_DIM;
    }
#pragma unroll
    for (int i = 0; i < 32; i += 8)
        tile[ty + i][tx] = (bf16)src[(size_t)(r0 + ty + i) * C + c0 + tx];
    __syncthreads();
#pragma unroll
    for (int i = 0; i < 32; i += 8)
        dst[(size_t)(c0 + ty + i) * R + r0 + tx] = tile[tx][ty + i];
}

// ---------------- batched bf16 transpose: dst[z][c][r] = src[z][r][c] ----------------
__global__ __launch_bounds__(256) void transpose2d(const bf16* __restrict__ src,
                                                   bf16* __restrict__ dst, int R, int C) {
    __shared__ bf16 tile[32][33];
    size_t zoff = (size_t)blockIdx.z * R * C;
    src += zoff; dst += zoff;
    int r0 = blockIdx.x * 32, c0 = blockIdx.y * 32;
    int tx = threadIdx.x & 31, ty = threadIdx.x >> 5;
#pragma unroll
    for (int i = 0; i < 32; i += 8) tile[ty + i][tx] = src[(size_t)(r0 + ty + i) * C + c0 + tx];
    __syncthreads();
#pragma unroll
    for (int i = 0; i < 32; i += 8) dst[(size_t)(c0 + ty + i) * R + r0 + tx] = tile[tx][ty + i];
}

// ---------------- GEMM: C = (A[4096x1024] * BT^T + bias) * scale ----------------
struct GemmPtrs { const bf16* A; const bf16* BT; const float* bias; bf16* C; float* Cf; float scale; };
struct GemmArgs { GemmPtrs p[3]; int mode; };

__global__ __launch_bounds__(256) void gemm_bt(GemmArgs args) {
    __shared__ __align__(16) bf16 As[128 * 32];
    __shared__ __align__(16) bf16 Bs[128 * 32];
    const GemmPtrs P = args.p[blockIdx.z];
    const int tid = threadIdx.x, wave = tid >> 6, lane = tid & 63;
    const int quad = lane >> 4, l15 = lane & 15;
    const int bm = blockIdx.x * 128, bn = blockIdx.y * 128;
    const int wm = (wave >> 1) * 64, wn = (wave & 1) * 64;

    floatx4 acc[4][4];
#pragma unroll
    for (int i = 0; i < 4; i++)
#pragma unroll
        for (int j = 0; j < 4; j++) acc[i][j] = (floatx4){0.f, 0.f, 0.f, 0.f};

    const int srow = (lane >> 2);
    const int scol = (((lane & 3) ^ ((srow >> 1) & 3)) << 3);  // swizzled source chunk
    const int ck = ((quad ^ ((l15 >> 1) & 3)) << 3);           // swizzled read chunk
    for (int k0 = 0; k0 < 1024; k0 += 32) {
#pragma unroll
        for (int it = 0; it < 2; ++it) {
            int issue = it * 4 + wave;
            int row = issue * 16 + srow;
            async_ld16(P.A + (size_t)(bm + row) * 1024 + k0 + scol, &As[issue * 512]);
            async_ld16(P.BT + (size_t)(bn + row) * 1024 + k0 + scol, &Bs[issue * 512]);
        }
        __syncthreads();
        bf16x8 af[4], bfr[4];
#pragma unroll
        for (int mi = 0; mi < 4; mi++)
            af[mi] = *(const bf16x8*)&As[(wm + mi * 16 + l15) * 32 + ck];
#pragma unroll
        for (int ni = 0; ni < 4; ni++)
            bfr[ni] = *(const bf16x8*)&Bs[(wn + ni * 16 + l15) * 32 + ck];
#pragma unroll
        for (int mi = 0; mi < 4; mi++)
#pragma unroll
            for (int ni = 0; ni < 4; ni++) acc[mi][ni] = mfma16(af[mi], bfr[ni], acc[mi][ni]);
        __syncthreads();
    }
#pragma unroll
    for (int ni = 0; ni < 4; ni++) {
        int col = bn + wn + ni * 16 + l15;
        float bb = P.bias[col];
#pragma unroll
        for (int mi = 0; mi < 4; mi++) {
#pragma unroll
            for (int r = 0; r < 4; r++) {
                int row = bm + wm + mi * 16 + quad * 4 + r;
                float v = (acc[mi][ni][r] + bb) * P.scale;
                if (args.mode == 0) {
                    P.Cf[(size_t)row * 1024 + col] = v;
                } else {
                    int b = row >> 11, s2 = row & 2047, h = col >> 6, hd = col & 63;
                    P.C[(((size_t)(b * H_CNT + h)) * S_LEN + s2) * HD_DIM + hd] = (bf16)v;
                }
            }
        }
    }
}

// ---------------- flash attention: 3-deep counted-vmcnt pipeline, 64-t rounds ----------------
// Structure change vs R1 (which was counter-correct but time-neutral -> drain stall was the
// real cost): tiles staged 2 rounds ahead into a 3-buffer ring; each round does
// s_waitcnt vmcnt(4) (drain ONLY the tile about to be read; the next tile's 4 loads stay in
// flight ACROSS the barrier, T4) + ONE raw s_barrier (serves both "tile ready" and "previous
// round's readers done -> safe to overwrite" fences). No vmcnt(0) in the main loop.
// Staging addresses are 4 incremented pointers (was ~80 VALU/round of rebuilt 64-bit math).
// Compute body per 64-t tile unchanged (QK -> exp2 -> T12 permlane P-frags -> PV).
__global__ __launch_bounds__(256) void attn(const bf16* __restrict__ Qg, const bf16* __restrict__ Kg,
                                            const bf16* __restrict__ Vtg, bf16* __restrict__ ctx) {
    __shared__ __align__(16) bf16 Ks[3][4096];    // [buf][c=8][t=64][8]
    __shared__ __align__(16) bf16 Vs[3][4096];    // [buf][tc=8][hd=64][8]
    const int tid = threadIdx.x, wave = tid >> 6, lane = tid & 63;
    const int l31 = lane & 31, half = lane >> 5;
    const int bid = blockIdx.x;
    const int bh = (bid >> 1) & 31;                       // L2 swizzle bijection
    const int qb = ((bid >> 6) << 1) | (bid & 1);
    const int q0blk = qb * 128;
    const bf16* Kp = Kg + (size_t)bh * S_LEN * HD_DIM;
    const bf16* Vp = Vtg + (size_t)bh * HD_DIM * S_LEN;

    // per-thread staging geometry: issue i = it*4+wave (it in {0,1}); flat f = i*512+lane*8
    // K layout [c=8][t=64][8]: c=f>>9, t=(f>>3)&63 ; src = Kp + (t0+t)*64 + c*8
    // V layout [tc=8][hd=64][8]: tc=f>>9, hd=(f>>3)&63 ; src = Vp + hd*2048 + t0 + tc*8
    const int i0 = wave, i1 = 4 + wave;
    const int f0 = i0 * 512 + lane * 8, f1 = i1 * 512 + lane * 8;
    const int c0i = f0 >> 9, r0i = (f0 >> 3) & 63;
    const int c1i = f1 >> 9, r1i = (f1 >> 3) & 63;
    const bf16* kg0 = Kp + (size_t)r0i * HD_DIM + c0i * 8;
    const bf16* kg1 = Kp + (size_t)r1i * HD_DIM + c1i * 8;
    const bf16* vg0 = Vp + (size_t)r0i * S_LEN + c0i * 8;
    const bf16* vg1 = Vp + (size_t)r1i * S_LEN + c1i * 8;

#define STAGE(BUF) do { \
        async_ld16(kg0, &Ks[BUF][i0 * 512]); \
        async_ld16(kg1, &Ks[BUF][i1 * 512]); \
        async_ld16(vg0, &Vs[BUF][i0 * 512]); \
        async_ld16(vg1, &Vs[BUF][i1 * 512]); \
        kg0 += 64 * HD_DIM; kg1 += 64 * HD_DIM; vg0 += 64; vg1 += 64; \
    } while (0)

    // prologue: stage tiles 0,1; load Q frags; full drain once (outside the hot loop)
    STAGE(0);
    STAGE(1);
    bf16x8 qf[4];
    {
        const bf16* qrow = Qg + ((size_t)bh * S_LEN + q0blk + wave * 32 + l31) * HD_DIM;
#pragma unroll
        for (int kb = 0; kb < 4; ++kb)
            qf[kb] = *(const bf16x8*)(qrow + (2 * kb + half) * 8);
    }
    __syncthreads();

    float l_i = 0.f;
    floatx16 o0 = {0}, o1 = {0};   // O^T strips: rows hd 0-31 / 32-63, col q=l31

    auto compute = [&](const bf16* Kt, const bf16* Vt) {
        // QK^T: sc[strip] rows t = 32*strip + (e&3)+8*(e>>2)+4*half, col q = l31
        floatx16 sc0 = {0}, sc1 = {0};
        __builtin_amdgcn_s_setprio(1);
#pragma unroll
        for (int kb = 0; kb < 4; ++kb) {
            bf16x8 k0 = *(const bf16x8*)&Kt[(2 * kb + half) * 512 + l31 * 8];
            bf16x8 k1 = *(const bf16x8*)&Kt[(2 * kb + half) * 512 + (32 + l31) * 8];
            sc0 = mfma32(k0, qf[kb], sc0);
            sc1 = mfma32(k1, qf[kb], sc1);
        }
        __builtin_amdgcn_s_setprio(0);
        // no-max softmax: P = exp2(score); pack to bf16x2 words in-register (T12).
        float rs = 0.f;
        int w0[8], w1[8];
#pragma unroll
        for (int e = 0; e < 16; e += 2) {   // strip 0: t = 0..31
            float p0 = __builtin_amdgcn_exp2f(sc0[e]);
            float p1 = __builtin_amdgcn_exp2f(sc0[e + 1]);
            rs += p0 + p1;
            bf16x2 t2 = {(bf16)p0, (bf16)p1};
            w0[e >> 1] = __builtin_bit_cast(int, t2);
        }
#pragma unroll
        for (int e = 0; e < 16; e += 2) {   // strip 1: t = 32..63
            float p0 = __builtin_amdgcn_exp2f(sc1[e]);
            float p1 = __builtin_amdgcn_exp2f(sc1[e + 1]);
            rs += p0 + p1;
            bf16x2 t2 = {(bf16)p0, (bf16)p1};
            w1[e >> 1] = __builtin_bit_cast(int, t2);
        }
        l_i += rs;
        bf16x8 pfr[4];
        pfr[0] = mkfrag(w0[0], w0[1], w0[2], w0[3]);
        pfr[1] = mkfrag(w0[4], w0[5], w0[6], w0[7]);
        pfr[2] = mkfrag(w1[0], w1[1], w1[2], w1[3]);
        pfr[3] = mkfrag(w1[4], w1[5], w1[6], w1[7]);
        // PV: O^T[hd][q] += V^T-frag x P-frag
        __builtin_amdgcn_s_setprio(1);
#pragma unroll
        for (int kb = 0; kb < 4; ++kb) {
            bf16x8 v0 = *(const bf16x8*)&Vt[(2 * kb + half) * 512 + l31 * 8];
            bf16x8 v1 = *(const bf16x8*)&Vt[(2 * kb + half) * 512 + (32 + l31) * 8];
            o0 = mfma32(v0, pfr[kb], o0);
            o1 = mfma32(v1, pfr[kb], o1);
        }
        __builtin_amdgcn_s_setprio(0);
    };

    // main loop: 32 tiles of 64 t. Round rd: wait tile rd (vmcnt(4) leaves tile rd+1 in
    // flight), barrier, stage tile rd+2 into buf (rd+2)%3, compute buf rd%3.
    for (int it3 = 0; it3 < 10; ++it3) {
        VMWAIT(4); __builtin_amdgcn_s_barrier();
        STAGE(2);  compute(&Ks[0][0], &Vs[0][0]);
        VMWAIT(4); __builtin_amdgcn_s_barrier();
        STAGE(0);  compute(&Ks[1][0], &Vs[1][0]);
        VMWAIT(4); __builtin_amdgcn_s_barrier();
        STAGE(1);  compute(&Ks[2][0], &Vs[2][0]);
    }
    VMWAIT(4); __builtin_amdgcn_s_barrier();
    compute(&Ks[0][0], &Vs[0][0]);                 // round 30
    VMWAIT(0); __builtin_amdgcn_s_barrier();
    compute(&Ks[1][0], &Vs[1][0]);                 // round 31
#undef STAGE

    // combine the two halves' partial l (disjoint t-subsets, same q)
    l_i += __shfl_xor(l_i, 32);
    __syncthreads();   // Ks about to be reused as epilogue scratch; other waves may still read
    // epilogue: normalize, transpose O^T->O via per-wave LDS slab, coalesced store
    int b = bh >> 4, hh = bh & 15;
    float inv = 1.f / l_i;
    bf16* Sw = &Ks[0][0] + wave * 1280;   // 32 q x 40 (padded) bf16 per wave
#pragma unroll
    for (int s2 = 0; s2 < 2; ++s2) {
        const floatx16 oo = s2 ? o1 : o0;
#pragma unroll
        for (int e = 0; e < 16; ++e) {
            int hd = (e & 3) + 8 * (e >> 2) + 4 * half;
            Sw[l31 * 40 + hd] = (bf16)(oo[e] * inv);  // [q=32][hd pad 40]
        }
#pragma unroll
        for (int p = 0; p < 2; ++p) {
            int q = p * 16 + (lane >> 2), part = lane & 3;
            bf16x8 v = *(const bf16x8*)&Sw[q * 40 + part * 8];
            int s = q0blk + wave * 32 + q;
            *(bf16x8*)&ctx[((size_t)(b * S_LEN + s)) * D_DIM + hh * 64 + s2 * 32 + part * 8] = v;
        }
    }
}

extern "C" void kernel_launch(void* const* d_in, const int* in_sizes, int n_in,
                              void* d_out, int out_size, void* d_ws, size_t ws_size,
                              hipStream_t stream) {
    const float* query = (const float*)d_in[0];
    const float* key   = (const float*)d_in[1];
    const float* value = (const float*)d_in[2];
    const float* Wq = (const float*)d_in[3];
    const float* bq = (const float*)d_in[4];
    const float* Wk = (const float*)d_in[5];
    const float* bk = (const float*)d_in[6];
    const float* Wv = (const float*)d_in[7];
    const float* bv = (const float*)d_in[8];
    const float* Wo = (const float*)d_in[9];
    const float* bo = (const float*)d_in[10];
    float* out = (float*)d_out;

    bf16* ws = (bf16*)d_ws;
    const size_t ASZ = (size_t)M_ROWS * D_DIM;
    const size_t WSZ = (size_t)H_CNT * D_DIM * HD_DIM;
    const size_t TSZ = (size_t)B_SZ * H_CNT * S_LEN * HD_DIM;
    bf16* Qc  = ws;
    bf16* Kc  = Qc + ASZ;
    bf16* Vc  = Kc + ASZ;
    bf16* WqT = Vc + ASZ;
    bf16* WkT = WqT + WSZ;
    bf16* WvT = WkT + WSZ;
    bf16* WoT = WvT + WSZ;
    bf16* Qb  = WoT + (size_t)D_DIM * D_DIM;  // [b,h,s,hd]
    bf16* Kb  = Qb + TSZ;
    bf16* Vb  = Kb + TSZ;
    bf16* Vtb = Vb + TSZ;                     // [b,h,hd,s]
    bf16* ctx = Vtb + TSZ;                    // [b,s,D]

    dim3 blk(256);

    PrepArgs pa;
    pa.cast_src[0] = query; pa.cast_src[1] = key; pa.cast_src[2] = value;
    pa.cast_dst[0] = Qc;    pa.cast_dst[1] = Kc;  pa.cast_dst[2] = Vc;
    pa.w_src[0] = Wq; pa.w_src[1] = Wk; pa.w_src[2] = Wv;
    pa.w_dst[0] = WqT; pa.w_dst[1] = WkT; pa.w_dst[2] = WvT;
    pa.wo = Wo; pa.wo_t = WoT;
    prep<<<dim3(16384), blk, 0, stream>>>(pa);

    GemmArgs qkv;
    qkv.p[0] = {Qc, WqT, bq, Qb, nullptr, QSCALE};
    qkv.p[1] = {Kc, WkT, bk, Kb, nullptr, 1.0f};
    qkv.p[2] = {Vc, WvT, bv, Vb, nullptr, 1.0f};
    qkv.mode = 1;
    gemm_bt<<<dim3(32, 8, 3), blk, 0, stream>>>(qkv);

    transpose2d<<<dim3(64, 2, 32), blk, 0, stream>>>(Vb, Vtb, 2048, 64);

    attn<<<dim3(512), blk, 0, stream>>>(Qb, Kb, Vtb, ctx);

    GemmArgs og;
    og.p[0] = {ctx, WoT, bo, nullptr, out, 1.0f};
    og.p[1] = og.p[0]; og.p[2] = og.p[0];
    og.mode = 0;
    gemm_bt<<<dim3(32, 8, 1), blk, 0, stream>>>(og);
}

// Round 3
// 236.464 us; speedup vs baseline: 1.0677x; 1.0677x over previous
//
#include <hip/hip_runtime.h>
#include <hip/hip_bf16.h>

typedef __bf16 bf16;
typedef __bf16 bf16x8 __attribute__((ext_vector_type(8)));
typedef __bf16 bf16x4 __attribute__((ext_vector_type(4)));
typedef __bf16 bf16x2 __attribute__((ext_vector_type(2)));
typedef float floatx4 __attribute__((ext_vector_type(4)));
typedef float floatx16 __attribute__((ext_vector_type(16)));

#define B_SZ 2
#define S_LEN 2048
#define D_DIM 1024
#define H_CNT 16
#define HD_DIM 64
#define M_ROWS 4096   // B*S
#define QSCALE 0.18033688011112042f  // 0.125 * log2(e): scores come out in base-2 domain

__device__ __forceinline__ void async_ld16(const bf16* g, bf16* s) {
    __builtin_amdgcn_global_load_lds((const __attribute__((address_space(1))) void*)g,
                                     (__attribute__((address_space(3))) void*)s, 16, 0, 0);
}

__device__ __forceinline__ floatx4 mfma16(bf16x8 a, bf16x8 b, floatx4 c) {
    return __builtin_amdgcn_mfma_f32_16x16x32_bf16(a, b, c, 0, 0, 0);
}
__device__ __forceinline__ floatx16 mfma32(bf16x8 a, bf16x8 b, floatx16 c) {
    return __builtin_amdgcn_mfma_f32_32x32x16_bf16(a, b, c, 0, 0, 0);
}

// ---------------- merged prep: input casts + all weight transposes, one launch ----------------
struct PrepArgs {
    const float* cast_src[3]; bf16* cast_dst[3];
    const float* w_src[3];    bf16* w_dst[3];
    const float* wo;          bf16* wo_t;
};
__global__ __launch_bounds__(256) void prep(PrepArgs a) {
    __shared__ bf16 tile[32][33];
    const int bx = blockIdx.x, tid = threadIdx.x;
    if (bx < 12288) {
        const int t = bx >> 12, blk = bx & 4095;
        const float* s = a.cast_src[t];
        bf16* d = a.cast_dst[t];
        size_t i = ((size_t)blk * 256 + tid) * 4;
        float4 v = *(const float4*)(s + i);
        bf16x4 o = { (bf16)v.x, (bf16)v.y, (bf16)v.z, (bf16)v.w };
        *(bf16x4*)(d + i) = o;
        return;
    }
    int tx = tid & 31, ty = tid >> 5;
    const float* src; bf16* dst; int r0, c0, C, R;
    if (bx < 15360) {
        int idx = bx - 12288;
        int z = idx >> 6, xy = idx & 63;
        int mat = z >> 4, head = z & 15;
        src = a.w_src[mat] + (size_t)head * D_DIM * HD_DIM;  // [1024][64]
        dst = a.w_dst[mat] + (size_t)head * D_DIM * HD_DIM;  // [64][1024]
        r0 = (xy & 31) * 32; c0 = (xy >> 5) * 32; C = HD_DIM; R = D_DIM;
    } else {
        int idx = bx - 15360;
        src = a.wo; dst = a.wo_t;
        r0 = (idx & 31) * 32; c0 = (idx >> 5) * 32; C = D_DIM; R = D_DIM;
    }
#pragma unroll
    for (int i = 0; i < 32; i += 8)
        tile[ty + i][tx] = (bf16)src[(size_t)(r0 + ty + i) * C + c0 + tx];
    __syncthreads();
#pragma unroll
    for (int i = 0; i < 32; i += 8)
        dst[(size_t)(c0 + ty + i) * R + r0 + tx] = tile[tx][ty + i];
}

// ---------------- GEMM: C = (A[4096x1024] * BT^T + bias) * scale ----------------
// per-slice mode: 0 = f32 out [row][col]; 1 = bf16 [b,h,s,hd]; 2 = bf16 V^T [b,h,hd,s]
// (mode 2 replaces the old standalone transpose2d kernel: same store count, different
//  addresses -- saves a 16MB HBM round-trip plus one dispatch.)
struct GemmPtrs { const bf16* A; const bf16* BT; const float* bias; bf16* C; float* Cf;
                  float scale; int mode; };
struct GemmArgs { GemmPtrs p[3]; };

__global__ __launch_bounds__(256) void gemm_bt(GemmArgs args) {
    __shared__ __align__(16) bf16 As[128 * 32];
    __shared__ __align__(16) bf16 Bs[128 * 32];
    const GemmPtrs P = args.p[blockIdx.z];
    const int tid = threadIdx.x, wave = tid >> 6, lane = tid & 63;
    const int quad = lane >> 4, l15 = lane & 15;
    const int bm = blockIdx.x * 128, bn = blockIdx.y * 128;
    const int wm = (wave >> 1) * 64, wn = (wave & 1) * 64;

    floatx4 acc[4][4];
#pragma unroll
    for (int i = 0; i < 4; i++)
#pragma unroll
        for (int j = 0; j < 4; j++) acc[i][j] = (floatx4){0.f, 0.f, 0.f, 0.f};

    const int srow = (lane >> 2);
    const int scol = (((lane & 3) ^ ((srow >> 1) & 3)) << 3);  // swizzled source chunk
    const int ck = ((quad ^ ((l15 >> 1) & 3)) << 3);           // swizzled read chunk
    for (int k0 = 0; k0 < 1024; k0 += 32) {
#pragma unroll
        for (int it = 0; it < 2; ++it) {
            int issue = it * 4 + wave;
            int row = issue * 16 + srow;
            async_ld16(P.A + (size_t)(bm + row) * 1024 + k0 + scol, &As[issue * 512]);
            async_ld16(P.BT + (size_t)(bn + row) * 1024 + k0 + scol, &Bs[issue * 512]);
        }
        __syncthreads();
        bf16x8 af[4], bfr[4];
#pragma unroll
        for (int mi = 0; mi < 4; mi++)
            af[mi] = *(const bf16x8*)&As[(wm + mi * 16 + l15) * 32 + ck];
#pragma unroll
        for (int ni = 0; ni < 4; ni++)
            bfr[ni] = *(const bf16x8*)&Bs[(wn + ni * 16 + l15) * 32 + ck];
#pragma unroll
        for (int mi = 0; mi < 4; mi++)
#pragma unroll
            for (int ni = 0; ni < 4; ni++) acc[mi][ni] = mfma16(af[mi], bfr[ni], acc[mi][ni]);
        __syncthreads();
    }
#pragma unroll
    for (int ni = 0; ni < 4; ni++) {
        int col = bn + wn + ni * 16 + l15;
        float bb = P.bias[col];
#pragma unroll
        for (int mi = 0; mi < 4; mi++) {
#pragma unroll
            for (int r = 0; r < 4; r++) {
                int row = bm + wm + mi * 16 + quad * 4 + r;
                float v = (acc[mi][ni][r] + bb) * P.scale;
                if (P.mode == 0) {
                    P.Cf[(size_t)row * 1024 + col] = v;
                } else {
                    int b = row >> 11, s2 = row & 2047, h = col >> 6, hd = col & 63;
                    if (P.mode == 1)
                        P.C[(((size_t)(b * H_CNT + h)) * S_LEN + s2) * HD_DIM + hd] = (bf16)v;
                    else  // mode 2: V^T [b,h,hd,s]
                        P.C[(((size_t)(b * H_CNT + h)) * HD_DIM + hd) * S_LEN + s2] = (bf16)v;
                }
            }
        }
    }
}

// ---------------- flash attention, 32x32x16 MFMA, no-max softmax, 128-t rounds ----------------
// R0 body verbatim (best measured: 62.8us). Pipeline restructures (R2) and in-reg P (R1)
// both measured neutral-to-worse: kernel is latency-bound at the grid-capped occupancy
// (512 blocks = 2/CU) and the P LDS round-trip / end-of-round drain are NOT on the
// critical path (R1/R2 A/B evidence).
__global__ __launch_bounds__(256) void attn(const bf16* __restrict__ Qg, const bf16* __restrict__ Kg,
                                            const bf16* __restrict__ Vtg, bf16* __restrict__ ctx) {
    __shared__ __align__(16) bf16 Ks[2][8192];    // [sub=2][c=8][t=64][8] dbuf
    __shared__ __align__(16) bf16 Vs[2][8192];    // [sub=2][tc=8][hd=64][8] dbuf
    __shared__ __align__(16) bf16 Ps[4][2048];    // per-wave P [tc=8][q=32][8]
    const int tid = threadIdx.x, wave = tid >> 6, lane = tid & 63;
    const int l31 = lane & 31, half = lane >> 5;
    const int bid = blockIdx.x;
    const int bh = (bid >> 1) & 31;                       // L2 swizzle bijection
    const int qb = ((bid >> 6) << 1) | (bid & 1);
    const int q0blk = qb * 128;
    const bf16* Kp = Kg + (size_t)bh * S_LEN * HD_DIM;
    const bf16* Vp = Vtg + (size_t)bh * HD_DIM * S_LEN;

    // staging decomposition: issue i in [0,16), flat f = i*512 + lane*8
    // sub = f>>12, c = (f&4095)>>9, r = (f>>3)&63
    // stage round 0 (tiles 0,1)
#pragma unroll
    for (int it = 0; it < 4; ++it) {
        int i = it * 4 + wave;
        int f = i * 512 + lane * 8;
        int sub = f >> 12, rem = f & 4095;
        int c = rem >> 9, r = (rem >> 3) & 63;
        async_ld16(Kp + (size_t)(sub * 64 + r) * HD_DIM + c * 8, &Ks[0][i * 512]);
        async_ld16(Vp + (size_t)r * S_LEN + sub * 64 + c * 8, &Vs[0][i * 512]);
    }
    // Q B-frags from global: B[q=wave*32+l31][k=(2kb+half)*8 + j]
    bf16x8 qf[4];
    {
        const bf16* qrow = Qg + ((size_t)bh * S_LEN + q0blk + wave * 32 + l31) * HD_DIM;
#pragma unroll
        for (int kb = 0; kb < 4; ++kb)
            qf[kb] = *(const bf16x8*)(qrow + (2 * kb + half) * 8);
    }
    __syncthreads();

    bf16* Pw = Ps[wave];
    float l_i = 0.f;
    floatx16 o0 = {0}, o1 = {0};   // O^T strips: rows hd 0-31 / 32-63, col q=l31

    for (int rd = 0; rd < 16; ++rd) {
        const int cur = rd & 1;
        if (rd < 15) {  // prefetch next round's 2 tiles
            int t0n = (rd + 1) * 128;
#pragma unroll
            for (int it = 0; it < 4; ++it) {
                int i = it * 4 + wave;
                int f = i * 512 + lane * 8;
                int sub = f >> 12, rem = f & 4095;
                int c = rem >> 9, r = (rem >> 3) & 63;
                async_ld16(Kp + (size_t)(t0n + sub * 64 + r) * HD_DIM + c * 8, &Ks[cur ^ 1][i * 512]);
                async_ld16(Vp + (size_t)r * S_LEN + t0n + sub * 64 + c * 8, &Vs[cur ^ 1][i * 512]);
            }
        }
#pragma unroll
        for (int sub = 0; sub < 2; ++sub) {
            const bf16* Kt = &Ks[cur][sub * 4096];
            const bf16* Vt = &Vs[cur][sub * 4096];
            // QK^T: sc[strip] rows t = 32*strip + (e&3)+8*(e>>2)+4*half, col q = l31
            floatx16 sc0 = {0}, sc1 = {0};
#pragma unroll
            for (int kb = 0; kb < 4; ++kb) {
                bf16x8 k0 = *(const bf16x8*)&Kt[(2 * kb + half) * 512 + l31 * 8];
                bf16x8 k1 = *(const bf16x8*)&Kt[(2 * kb + half) * 512 + (32 + l31) * 8];
                sc0 = mfma32(k0, qf[kb], sc0);
                sc1 = mfma32(k1, qf[kb], sc1);
            }
            // no-max softmax: P = exp2(score), native v_exp_f32
            float rs = 0.f;
#pragma unroll
            for (int e = 0; e < 16; e += 2) {   // strip 0: t = 0..31
                float p0 = __builtin_amdgcn_exp2f(sc0[e]);
                float p1 = __builtin_amdgcn_exp2f(sc0[e + 1]);
                rs += p0 + p1;
                *(bf16x2*)&Pw[(e >> 2) * 256 + l31 * 8 + (e & 3) + 4 * half] = (bf16x2){(bf16)p0, (bf16)p1};
            }
#pragma unroll
            for (int e = 0; e < 16; e += 2) {   // strip 1: t = 32..63
                float p0 = __builtin_amdgcn_exp2f(sc1[e]);
                float p1 = __builtin_amdgcn_exp2f(sc1[e + 1]);
                rs += p0 + p1;
                *(bf16x2*)&Pw[(4 + (e >> 2)) * 256 + l31 * 8 + (e & 3) + 4 * half] = (bf16x2){(bf16)p0, (bf16)p1};
            }
            l_i += rs;
            // PV: O^T[hd][q] += V^T-frag x P-frag
#pragma unroll
            for (int kb = 0; kb < 4; ++kb) {
                bf16x8 pf = *(const bf16x8*)&Pw[(2 * kb + half) * 256 + l31 * 8];
                bf16x8 v0 = *(const bf16x8*)&Vt[(2 * kb + half) * 512 + l31 * 8];
                bf16x8 v1 = *(const bf16x8*)&Vt[(2 * kb + half) * 512 + (32 + l31) * 8];
                o0 = mfma32(v0, pf, o0);
                o1 = mfma32(v1, pf, o1);
            }
        }
        __syncthreads();
    }
    // combine the two halves' partial l (disjoint t-subsets, same q)
    l_i += __shfl_xor(l_i, 32);
    // epilogue: normalize, transpose O^T->O via per-wave LDS slab, coalesced store
    int b = bh >> 4, hh = bh & 15;
    float inv = 1.f / l_i;
#pragma unroll
    for (int s2 = 0; s2 < 2; ++s2) {
        const floatx16 oo = s2 ? o1 : o0;
#pragma unroll
        for (int e = 0; e < 16; ++e) {
            int hd = (e & 3) + 8 * (e >> 2) + 4 * half;
            Pw[l31 * 40 + hd] = (bf16)(oo[e] * inv);  // [q=32][hd pad 40]
        }
#pragma unroll
        for (int p = 0; p < 2; ++p) {
            int q = p * 16 + (lane >> 2), part = lane & 3;
            bf16x8 v = *(const bf16x8*)&Pw[q * 40 + part * 8];
            int s = q0blk + wave * 32 + q;
            *(bf16x8*)&ctx[((size_t)(b * S_LEN + s)) * D_DIM + hh * 64 + s2 * 32 + part * 8] = v;
        }
    }
}

extern "C" void kernel_launch(void* const* d_in, const int* in_sizes, int n_in,
                              void* d_out, int out_size, void* d_ws, size_t ws_size,
                              hipStream_t stream) {
    const float* query = (const float*)d_in[0];
    const float* key   = (const float*)d_in[1];
    const float* value = (const float*)d_in[2];
    const float* Wq = (const float*)d_in[3];
    const float* bq = (const float*)d_in[4];
    const float* Wk = (const float*)d_in[5];
    const float* bk = (const float*)d_in[6];
    const float* Wv = (const float*)d_in[7];
    const float* bv = (const float*)d_in[8];
    const float* Wo = (const float*)d_in[9];
    const float* bo = (const float*)d_in[10];
    float* out = (float*)d_out;

    bf16* ws = (bf16*)d_ws;
    const size_t ASZ = (size_t)M_ROWS * D_DIM;
    const size_t WSZ = (size_t)H_CNT * D_DIM * HD_DIM;
    const size_t TSZ = (size_t)B_SZ * H_CNT * S_LEN * HD_DIM;
    bf16* Qc  = ws;
    bf16* Kc  = Qc + ASZ;
    bf16* Vc  = Kc + ASZ;
    bf16* WqT = Vc + ASZ;
    bf16* WkT = WqT + WSZ;
    bf16* WvT = WkT + WSZ;
    bf16* WoT = WvT + WSZ;
    bf16* Qb  = WoT + (size_t)D_DIM * D_DIM;  // [b,h,s,hd]
    bf16* Kb  = Qb + TSZ;
    bf16* Vtb = Kb + TSZ;                     // [b,h,hd,s] -- written directly by gemm mode 2
    bf16* ctx = Vtb + TSZ;                    // [b,s,D]

    dim3 blk(256);

    PrepArgs pa;
    pa.cast_src[0] = query; pa.cast_src[1] = key; pa.cast_src[2] = value;
    pa.cast_dst[0] = Qc;    pa.cast_dst[1] = Kc;  pa.cast_dst[2] = Vc;
    pa.w_src[0] = Wq; pa.w_src[1] = Wk; pa.w_src[2] = Wv;
    pa.w_dst[0] = WqT; pa.w_dst[1] = WkT; pa.w_dst[2] = WvT;
    pa.wo = Wo; pa.wo_t = WoT;
    prep<<<dim3(16384), blk, 0, stream>>>(pa);

    GemmArgs qkv;
    qkv.p[0] = {Qc, WqT, bq, Qb, nullptr, QSCALE, 1};
    qkv.p[1] = {Kc, WkT, bk, Kb, nullptr, 1.0f, 1};
    qkv.p[2] = {Vc, WvT, bv, Vtb, nullptr, 1.0f, 2};   // V writes V^T directly
    gemm_bt<<<dim3(32, 8, 3), blk, 0, stream>>>(qkv);

    attn<<<dim3(512), blk, 0, stream>>>(Qb, Kb, Vtb, ctx);

    GemmArgs og;
    og.p[0] = {ctx, WoT, bo, nullptr, out, 1.0f, 0};
    og.p[1] = og.p[0]; og.p[2] = og.p[0];
    gemm_bt<<<dim3(32, 8, 1), blk, 0, stream>>>(og);
}

// Round 4
// 221.872 us; speedup vs baseline: 1.1379x; 1.0658x over previous
//
#include <hip/hip_runtime.h>
#include <hip/hip_bf16.h>

typedef __bf16 bf16;
typedef __bf16 bf16x8 __attribute__((ext_vector_type(8)));
typedef __bf16 bf16x4 __attribute__((ext_vector_type(4)));
typedef __bf16 bf16x2 __attribute__((ext_vector_type(2)));
typedef float floatx4 __attribute__((ext_vector_type(4)));
typedef float floatx16 __attribute__((ext_vector_type(16)));
typedef int intx4 __attribute__((ext_vector_type(4)));

#define B_SZ 2
#define S_LEN 2048
#define D_DIM 1024
#define H_CNT 16
#define HD_DIM 64
#define M_ROWS 4096   // B*S
#define QSCALE 0.18033688011112042f  // 0.125 * log2(e): scores come out in base-2 domain

__device__ __forceinline__ void async_ld16(const bf16* g, bf16* s) {
    __builtin_amdgcn_global_load_lds((const __attribute__((address_space(1))) void*)g,
                                     (__attribute__((address_space(3))) void*)s, 16, 0, 0);
}

__device__ __forceinline__ floatx4 mfma16(bf16x8 a, bf16x8 b, floatx4 c) {
    return __builtin_amdgcn_mfma_f32_16x16x32_bf16(a, b, c, 0, 0, 0);
}
__device__ __forceinline__ floatx16 mfma32(bf16x8 a, bf16x8 b, floatx16 c) {
    return __builtin_amdgcn_mfma_f32_32x32x16_bf16(a, b, c, 0, 0, 0);
}

// T12 fragment assembly: one permlane32_swap fills two output words (validated R1: passed
// with absmax identical to LDS-P path).
__device__ __forceinline__ bf16x8 mkfrag(int a0, int a1, int b0, int b1) {
    asm("v_permlane32_swap_b32 %0, %1" : "+v"(a0), "+v"(b0));
    asm("v_permlane32_swap_b32 %0, %1" : "+v"(a1), "+v"(b1));
    intx4 q = {a0, a1, b0, b1};
    return __builtin_bit_cast(bf16x8, q);
}

// ---------------- merged prep: input casts + all weight transposes, one launch ----------------
struct PrepArgs {
    const float* cast_src[3]; bf16* cast_dst[3];
    const float* w_src[3];    bf16* w_dst[3];
    const float* wo;          bf16* wo_t;
};
__global__ __launch_bounds__(256) void prep(PrepArgs a) {
    __shared__ bf16 tile[32][33];
    const int bx = blockIdx.x, tid = threadIdx.x;
    if (bx < 12288) {
        const int t = bx >> 12, blk = bx & 4095;
        const float* s = a.cast_src[t];
        bf16* d = a.cast_dst[t];
        size_t i = ((size_t)blk * 256 + tid) * 4;
        float4 v = *(const float4*)(s + i);
        bf16x4 o = { (bf16)v.x, (bf16)v.y, (bf16)v.z, (bf16)v.w };
        *(bf16x4*)(d + i) = o;
        return;
    }
    int tx = tid & 31, ty = tid >> 5;
    const float* src; bf16* dst; int r0, c0, C, R;
    if (bx < 15360) {
        int idx = bx - 12288;
        int z = idx >> 6, xy = idx & 63;
        int mat = z >> 4, head = z & 15;
        src = a.w_src[mat] + (size_t)head * D_DIM * HD_DIM;  // [1024][64]
        dst = a.w_dst[mat] + (size_t)head * D_DIM * HD_DIM;  // [64][1024]
        r0 = (xy & 31) * 32; c0 = (xy >> 5) * 32; C = HD_DIM; R = D_DIM;
    } else {
        int idx = bx - 15360;
        src = a.wo; dst = a.wo_t;
        r0 = (idx & 31) * 32; c0 = (idx >> 5) * 32; C = D_DIM; R = D_DIM;
    }
#pragma unroll
    for (int i = 0; i < 32; i += 8)
        tile[ty + i][tx] = (bf16)src[(size_t)(r0 + ty + i) * C + c0 + tx];
    __syncthreads();
#pragma unroll
    for (int i = 0; i < 32; i += 8)
        dst[(size_t)(c0 + ty + i) * R + r0 + tx] = tile[tx][ty + i];
}

// ---------------- GEMM: C = (A[4096x1024] * BT^T + bias) * scale ----------------
// per-slice mode: 0 = f32 out [row][col]; 1 = bf16 [b,h,s,hd]; 2 = bf16 V^T [b,h,hd,s]
struct GemmPtrs { const bf16* A; const bf16* BT; const float* bias; bf16* C; float* Cf;
                  float scale; int mode; };
struct GemmArgs { GemmPtrs p[3]; };

__global__ __launch_bounds__(256) void gemm_bt(GemmArgs args) {
    __shared__ __align__(16) bf16 As[128 * 32];
    __shared__ __align__(16) bf16 Bs[128 * 32];
    const GemmPtrs P = args.p[blockIdx.z];
    const int tid = threadIdx.x, wave = tid >> 6, lane = tid & 63;
    const int quad = lane >> 4, l15 = lane & 15;
    const int bm = blockIdx.x * 128, bn = blockIdx.y * 128;
    const int wm = (wave >> 1) * 64, wn = (wave & 1) * 64;

    floatx4 acc[4][4];
#pragma unroll
    for (int i = 0; i < 4; i++)
#pragma unroll
        for (int j = 0; j < 4; j++) acc[i][j] = (floatx4){0.f, 0.f, 0.f, 0.f};

    const int srow = (lane >> 2);
    const int scol = (((lane & 3) ^ ((srow >> 1) & 3)) << 3);  // swizzled source chunk
    const int ck = ((quad ^ ((l15 >> 1) & 3)) << 3);           // swizzled read chunk
    for (int k0 = 0; k0 < 1024; k0 += 32) {
#pragma unroll
        for (int it = 0; it < 2; ++it) {
            int issue = it * 4 + wave;
            int row = issue * 16 + srow;
            async_ld16(P.A + (size_t)(bm + row) * 1024 + k0 + scol, &As[issue * 512]);
            async_ld16(P.BT + (size_t)(bn + row) * 1024 + k0 + scol, &Bs[issue * 512]);
        }
        __syncthreads();
        bf16x8 af[4], bfr[4];
#pragma unroll
        for (int mi = 0; mi < 4; mi++)
            af[mi] = *(const bf16x8*)&As[(wm + mi * 16 + l15) * 32 + ck];
#pragma unroll
        for (int ni = 0; ni < 4; ni++)
            bfr[ni] = *(const bf16x8*)&Bs[(wn + ni * 16 + l15) * 32 + ck];
#pragma unroll
        for (int mi = 0; mi < 4; mi++)
#pragma unroll
            for (int ni = 0; ni < 4; ni++) acc[mi][ni] = mfma16(af[mi], bfr[ni], acc[mi][ni]);
        __syncthreads();
    }
#pragma unroll
    for (int ni = 0; ni < 4; ni++) {
        int col = bn + wn + ni * 16 + l15;
        float bb = P.bias[col];
#pragma unroll
        for (int mi = 0; mi < 4; mi++) {
#pragma unroll
            for (int r = 0; r < 4; r++) {
                int row = bm + wm + mi * 16 + quad * 4 + r;
                float v = (acc[mi][ni][r] + bb) * P.scale;
                if (P.mode == 0) {
                    P.Cf[(size_t)row * 1024 + col] = v;
                } else {
                    int b = row >> 11, s2 = row & 2047, h = col >> 6, hd = col & 63;
                    if (P.mode == 1)
                        P.C[(((size_t)(b * H_CNT + h)) * S_LEN + s2) * HD_DIM + hd] = (bf16)v;
                    else  // mode 2: V^T [b,h,hd,s]
                        P.C[(((size_t)(b * H_CNT + h)) * HD_DIM + hd) * S_LEN + s2] = (bf16)v;
                }
            }
        }
    }
}

// ---------------- flash attention: t-split 2-way inside a 512-thread block ----------------
// Occupancy fix: q-parallelism alone caps at 2 waves/SIMD (2048 waves total). Waves 0-3
// process t=[0,1024), waves 4-7 t=[1024,2048) for the SAME 128 q rows -> 4 waves/SIMD.
// No-max softmax makes the merge linear: group 0 dumps unnormalized O^T + l into LDS,
// group 1 adds, normalizes once, stores. P in-register via T12 permlane (R1-validated)
// so LDS = 64KB (2 groups x 64-t K/V dbuf) and 2 blocks/CU fit.
__global__ __launch_bounds__(512, 4) void attn(const bf16* __restrict__ Qg, const bf16* __restrict__ Kg,
                                               const bf16* __restrict__ Vtg, bf16* __restrict__ ctx) {
    __shared__ __align__(16) bf16 smem[32768];    // 64 KB
    const int tid = threadIdx.x, wave = tid >> 6, lane = tid & 63;
    const int l31 = lane & 31, half = lane >> 5;
    const int grp = wave >> 2, wg = wave & 3;     // t-group, wave-in-group
    const int bid = blockIdx.x;
    const int bh = (bid >> 1) & 31;               // L2 swizzle bijection
    const int qb = ((bid >> 6) << 1) | (bid & 1);
    const int q0blk = qb * 128;
    const bf16* Kp = Kg + (size_t)bh * S_LEN * HD_DIM;
    const bf16* Vp = Vtg + (size_t)bh * HD_DIM * S_LEN;
    const int tbase = grp * 1024;

    // staging: per 64-t tile, K [c=8][t=64][8] (8KB) + V [tc=8][hd=64][8] (8KB) = 16 issues
    // of 1KB, shared by the group's 4 waves: issues i = wg, wg+4 for each of K and V.
    const int f0 = wg * 512 + lane * 8, f1 = (wg + 4) * 512 + lane * 8;
    const int kc0 = f0 >> 9, kt0 = (f0 >> 3) & 63;
    const int kc1 = f1 >> 9, kt1 = (f1 >> 3) & 63;
    bf16* const Kbase = smem + grp * 8192;
    bf16* const Vbase = smem + 16384 + grp * 8192;

#define STAGE(BUF, T0) do { \
        bf16* Kd = Kbase + (BUF) * 4096; \
        bf16* Vd = Vbase + (BUF) * 4096; \
        async_ld16(Kp + (size_t)((T0) + kt0) * HD_DIM + kc0 * 8, Kd + wg * 512); \
        async_ld16(Kp + (size_t)((T0) + kt1) * HD_DIM + kc1 * 8, Kd + (wg + 4) * 512); \
        async_ld16(Vp + (size_t)kt0 * S_LEN + (T0) + kc0 * 8, Vd + wg * 512); \
        async_ld16(Vp + (size_t)kt1 * S_LEN + (T0) + kc1 * 8, Vd + (wg + 4) * 512); \
    } while (0)

    STAGE(0, tbase);
    // Q B-frags from global: B[q=wg*32+l31][k=(2kb+half)*8 + j] (both groups load same rows)
    bf16x8 qf[4];
    {
        const bf16* qrow = Qg + ((size_t)bh * S_LEN + q0blk + wg * 32 + l31) * HD_DIM;
#pragma unroll
        for (int kb = 0; kb < 4; ++kb)
            qf[kb] = *(const bf16x8*)(qrow + (2 * kb + half) * 8);
    }
    __syncthreads();

    float l_i = 0.f;
    floatx16 o0 = {0}, o1 = {0};   // O^T strips: rows hd 0-31 / 32-63, col q=l31

    for (int rd = 0; rd < 16; ++rd) {
        const int cur = rd & 1;
        if (rd < 15) STAGE(cur ^ 1, tbase + (rd + 1) * 64);
        const bf16* Kt = Kbase + cur * 4096;
        const bf16* Vt = Vbase + cur * 4096;
        // QK^T: sc[strip] rows t = 32*strip + (e&3)+8*(e>>2)+4*half, col q = l31
        floatx16 sc0 = {0}, sc1 = {0};
        __builtin_amdgcn_s_setprio(1);
#pragma unroll
        for (int kb = 0; kb < 4; ++kb) {
            bf16x8 k0 = *(const bf16x8*)&Kt[(2 * kb + half) * 512 + l31 * 8];
            bf16x8 k1 = *(const bf16x8*)&Kt[(2 * kb + half) * 512 + (32 + l31) * 8];
            sc0 = mfma32(k0, qf[kb], sc0);
            sc1 = mfma32(k1, qf[kb], sc1);
        }
        __builtin_amdgcn_s_setprio(0);
        // no-max softmax: P = exp2(score); pack to bf16x2 words in-register (T12).
        float rs = 0.f;
        int w0[8], w1[8];
#pragma unroll
        for (int e = 0; e < 16; e += 2) {   // strip 0: t = 0..31
            float p0 = __builtin_amdgcn_exp2f(sc0[e]);
            float p1 = __builtin_amdgcn_exp2f(sc0[e + 1]);
            rs += p0 + p1;
            bf16x2 t2 = {(bf16)p0, (bf16)p1};
            w0[e >> 1] = __builtin_bit_cast(int, t2);
        }
#pragma unroll
        for (int e = 0; e < 16; e += 2) {   // strip 1: t = 32..63
            float p0 = __builtin_amdgcn_exp2f(sc1[e]);
            float p1 = __builtin_amdgcn_exp2f(sc1[e + 1]);
            rs += p0 + p1;
            bf16x2 t2 = {(bf16)p0, (bf16)p1};
            w1[e >> 1] = __builtin_bit_cast(int, t2);
        }
        l_i += rs;
        bf16x8 pfr[4];
        pfr[0] = mkfrag(w0[0], w0[1], w0[2], w0[3]);
        pfr[1] = mkfrag(w0[4], w0[5], w0[6], w0[7]);
        pfr[2] = mkfrag(w1[0], w1[1], w1[2], w1[3]);
        pfr[3] = mkfrag(w1[4], w1[5], w1[6], w1[7]);
        // PV: O^T[hd][q] += V^T-frag x P-frag
        __builtin_amdgcn_s_setprio(1);
#pragma unroll
        for (int kb = 0; kb < 4; ++kb) {
            bf16x8 v0 = *(const bf16x8*)&Vt[(2 * kb + half) * 512 + l31 * 8];
            bf16x8 v1 = *(const bf16x8*)&Vt[(2 * kb + half) * 512 + (32 + l31) * 8];
            o0 = mfma32(v0, pfr[kb], o0);
            o1 = mfma32(v1, pfr[kb], o1);
        }
        __builtin_amdgcn_s_setprio(0);
        __syncthreads();
    }
#undef STAGE

    // combine the two lane-halves' partial l (disjoint t-subsets, same q)
    l_i += __shfl_xor(l_i, 32);

    // linear t-group merge via LDS (loop already ended on a barrier -> smem free).
    // slabF: per g0-wave [32 q][66 pad] f32 (8448B x4 = 33792B); lA: 128 f32 @ byte 33792;
    // slab2 (bf16 transpose scratch for g1): byte 34816 + wg*2560. All regions disjoint.
    float* slabF = (float*)smem;
    float* lA = slabF + 4 * 2112;
    if (grp == 0) {
        float* S0 = slabF + wg * 2112;
#pragma unroll
        for (int s2 = 0; s2 < 2; ++s2) {
            const floatx16 oo = s2 ? o1 : o0;
#pragma unroll
            for (int e = 0; e < 16; ++e) {
                int hd = s2 * 32 + (e & 3) + 8 * (e >> 2) + 4 * half;
                S0[l31 * 66 + hd] = oo[e];     // unnormalized partial O^T
            }
        }
        if (lane < 32) lA[wg * 32 + l31] = l_i;
    }
    __syncthreads();
    if (grp == 1) {
        float* S0 = slabF + wg * 2112;
        float lt = l_i + lA[wg * 32 + l31];
        float inv = 1.f / lt;
        int b = bh >> 4, hh = bh & 15;
        bf16* Sw = smem + 17408 + wg * 1280;   // 32 q x 40 (padded) bf16
#pragma unroll
        for (int s2 = 0; s2 < 2; ++s2) {
            const floatx16 oo = s2 ? o1 : o0;
#pragma unroll
            for (int e = 0; e < 16; ++e) {
                int hd = (e & 3) + 8 * (e >> 2) + 4 * half;
                float v = (oo[e] + S0[l31 * 66 + s2 * 32 + hd]) * inv;
                Sw[l31 * 40 + hd] = (bf16)v;
            }
#pragma unroll
            for (int p = 0; p < 2; ++p) {
                int q = p * 16 + (lane >> 2), part = lane & 3;
                bf16x8 v = *(const bf16x8*)&Sw[q * 40 + part * 8];
                int s = q0blk + wg * 32 + q;
                *(bf16x8*)&ctx[((size_t)(b * S_LEN + s)) * D_DIM + hh * 64 + s2 * 32 + part * 8] = v;
            }
        }
    }
}

extern "C" void kernel_launch(void* const* d_in, const int* in_sizes, int n_in,
                              void* d_out, int out_size, void* d_ws, size_t ws_size,
                              hipStream_t stream) {
    const float* query = (const float*)d_in[0];
    const float* key   = (const float*)d_in[1];
    const float* value = (const float*)d_in[2];
    const float* Wq = (const float*)d_in[3];
    const float* bq = (const float*)d_in[4];
    const float* Wk = (const float*)d_in[5];
    const float* bk = (const float*)d_in[6];
    const float* Wv = (const float*)d_in[7];
    const float* bv = (const float*)d_in[8];
    const float* Wo = (const float*)d_in[9];
    const float* bo = (const float*)d_in[10];
    float* out = (float*)d_out;

    bf16* ws = (bf16*)d_ws;
    const size_t ASZ = (size_t)M_ROWS * D_DIM;
    const size_t WSZ = (size_t)H_CNT * D_DIM * HD_DIM;
    const size_t TSZ = (size_t)B_SZ * H_CNT * S_LEN * HD_DIM;
    bf16* Qc  = ws;
    bf16* Kc  = Qc + ASZ;
    bf16* Vc  = Kc + ASZ;
    bf16* WqT = Vc + ASZ;
    bf16* WkT = WqT + WSZ;
    bf16* WvT = WkT + WSZ;
    bf16* WoT = WvT + WSZ;
    bf16* Qb  = WoT + (size_t)D_DIM * D_DIM;  // [b,h,s,hd]
    bf16* Kb  = Qb + TSZ;
    bf16* Vtb = Kb + TSZ;                     // [b,h,hd,s] -- written directly by gemm mode 2
    bf16* ctx = Vtb + TSZ;                    // [b,s,D]

    dim3 blk(256);

    PrepArgs pa;
    pa.cast_src[0] = query; pa.cast_src[1] = key; pa.cast_src[2] = value;
    pa.cast_dst[0] = Qc;    pa.cast_dst[1] = Kc;  pa.cast_dst[2] = Vc;
    pa.w_src[0] = Wq; pa.w_src[1] = Wk; pa.w_src[2] = Wv;
    pa.w_dst[0] = WqT; pa.w_dst[1] = WkT; pa.w_dst[2] = WvT;
    pa.wo = Wo; pa.wo_t = WoT;
    prep<<<dim3(16384), blk, 0, stream>>>(pa);

    GemmArgs qkv;
    qkv.p[0] = {Qc, WqT, bq, Qb, nullptr, QSCALE, 1};
    qkv.p[1] = {Kc, WkT, bk, Kb, nullptr, 1.0f, 1};
    qkv.p[2] = {Vc, WvT, bv, Vtb, nullptr, 1.0f, 2};   // V writes V^T directly
    gemm_bt<<<dim3(32, 8, 3), blk, 0, stream>>>(qkv);

    attn<<<dim3(512), dim3(512), 0, stream>>>(Qb, Kb, Vtb, ctx);

    GemmArgs og;
    og.p[0] = {ctx, WoT, bo, nullptr, out, 1.0f, 0};
    og.p[1] = og.p[0]; og.p[2] = og.p[0];
    gemm_bt<<<dim3(32, 8, 1), blk, 0, stream>>>(og);
}